// Round 16
// baseline (443.962 us; speedup 1.0000x reference)
//
#include <hip/hip_runtime.h>

#define NN 65536
#define NE 1048576
#define HID 80

typedef unsigned int u32;
typedef unsigned short u16;
typedef unsigned long long u64;

__device__ __forceinline__ u16 f2bf(float f) {
  u32 u = __float_as_uint(f);
  u = (u + 0x7fffu + ((u >> 16) & 1u)) >> 16;  // RNE
  return (u16)u;
}
__device__ __forceinline__ float bfhi(u32 packed) {
  return __uint_as_float(packed & 0xffff0000u);
}
__device__ __forceinline__ float bflo(u32 packed) {
  return __uint_as_float(packed << 16);
}

// ---------------- input projection: h = x @ W_in + b_in ----------------
// hmain[n][64] = logical comps 0..63; htail[n][16] = comps 64..79 (L2-res.)
__global__ __launch_bounds__(256) void k_in(const float* __restrict__ x,
    const float* __restrict__ W, const float* __restrict__ b,
    u16* __restrict__ hmain, u16* __restrict__ htail) {
  int idx = blockIdx.x * 256 + threadIdx.x;
  if (idx >= NN * HID) return;
  int n = idx / HID, l = idx % HID;
  const float* xr = x + n * 16;
  float acc = b[l];
#pragma unroll
  for (int k = 0; k < 16; k++) acc += xr[k] * W[k * HID + l];
  u16 v = f2bf(acc);
  if (l < 64) hmain[(size_t)n * 64 + l] = v;
  else htail[(size_t)n * 16 + (l - 64)] = v;
}

// ---------------- CSR build ----------------
__global__ __launch_bounds__(256) void k_hist(const int* __restrict__ dst,
    int* __restrict__ counts, int* __restrict__ rank) {
  int base = blockIdx.x * 1024 + threadIdx.x;
#pragma unroll
  for (int k = 0; k < 4; k++) {
    int idx = base + k * 256;
    rank[idx] = atomicAdd(&counts[dst[idx]], 1);
  }
}

__global__ __launch_bounds__(256) void k_scan1(const int* __restrict__ counts,
    int* __restrict__ offsets, int* __restrict__ blocksum) {
  __shared__ int sc[256];
  int t = threadIdx.x;
  int base = blockIdx.x * 1024 + t * 4;
  int p0 = (counts[base] + 7) & ~7;
  int p1 = (counts[base + 1] + 7) & ~7;
  int p2 = (counts[base + 2] + 7) & ~7;
  int p3 = (counts[base + 3] + 7) & ~7;
  int s = p0 + p1 + p2 + p3;
  sc[t] = s;
  __syncthreads();
  for (int d = 1; d < 256; d <<= 1) {
    int v = (t >= d) ? sc[t - d] : 0;
    __syncthreads();
    sc[t] += v;
    __syncthreads();
  }
  int excl = sc[t] - s;
  offsets[base] = excl;
  offsets[base + 1] = excl + p0;
  offsets[base + 2] = excl + p0 + p1;
  offsets[base + 3] = excl + p0 + p1 + p2;
  if (t == 255) blocksum[blockIdx.x] = sc[255];
}

__global__ __launch_bounds__(64) void k_scan2(int* __restrict__ blocksum) {
  int t = threadIdx.x;
  int v = blocksum[t];
  int incl = v;
#pragma unroll
  for (int d = 1; d < 64; d <<= 1) {
    int o = __shfl_up(incl, d, 64);
    if (t >= d) incl += o;
  }
  blocksum[t] = incl - v;
}

__global__ __launch_bounds__(256) void k_scan3(int* __restrict__ offsets,
    const int* __restrict__ blocksum) {
  int i = blockIdx.x * 256 + threadIdx.x;
  offsets[i] += blocksum[i >> 10];
}

// zero ONLY the pad slots (coef=0 contributes nothing in gather)
__global__ __launch_bounds__(256) void k_pad(const int* __restrict__ counts,
    const int* __restrict__ offsets, uint4* __restrict__ erec) {
  int n = blockIdx.x * 256 + threadIdx.x;
  int deg = counts[n];
  int degp = (deg + 7) & ~7;
  int base = offsets[n];
  uint4 z = make_uint4(0u, 0u, 0u, 0u);
  for (int e = deg; e < degp; e++) erec[base + e] = z;
}

// pure scatter, no atomic: pos = offsets[dst] + rank
__global__ __launch_bounds__(256) void k_fill(const int* __restrict__ src,
    const int* __restrict__ dst, const float4* __restrict__ eattr,
    const int* __restrict__ offsets, const int* __restrict__ rank,
    uint4* __restrict__ erec) {
  int base = blockIdx.x * 1024 + threadIdx.x;
#pragma unroll
  for (int k = 0; k < 4; k++) {
    int idx = base + k * 256;
    int d = dst[idx];
    float4 ea = eattr[idx];
    int s = src[idx];
    u32 c01 = (u32)f2bf(ea.x) | ((u32)f2bf(ea.y) << 16);
    u32 c23 = (u32)f2bf(ea.z) | ((u32)f2bf(ea.w) << 16);
    int pos = offsets[d] + rank[idx];
    erec[pos] = make_uint4((u32)s, c01, c23, 0u);
  }
}

// ---------------- degree-bucket node sort ----------------
__global__ __launch_bounds__(256) void k_nbucket(const int* __restrict__ counts,
    int* __restrict__ dcnt, int* __restrict__ brank, int* __restrict__ bidx) {
  int n = blockIdx.x * 256 + threadIdx.x;
  int degp = (counts[n] + 7) & ~7;
  int b = 15 - min(degp >> 3, 15);
  int lane = threadIdx.x & 63;
  int base = 0;
#pragma unroll 1
  for (int bb = 0; bb < 16; bb++) {
    u64 m = __ballot(b == bb);
    if (b == bb) {
      int leader = __ffsll((long long)m) - 1;
      int lr = __popcll(m & ((lane == 63) ? ~0ull >> 1 : ((1ull << lane) - 1)));
      int bs = 0;
      if (lane == leader) bs = atomicAdd(&dcnt[bb], __popcll(m));
      bs = __shfl(bs, leader, 64);
      base = bs + lr;
    }
  }
  brank[n] = base;
  bidx[n] = b;
}

__global__ __launch_bounds__(64) void k_dscan(int* __restrict__ dcnt) {
  int t = threadIdx.x;
  if (t >= 16) return;
  int v = dcnt[t];
  int incl = v;
#pragma unroll
  for (int d = 1; d < 16; d <<= 1) {
    int o = __shfl_up(incl, d, 64);
    if (t >= d) incl += o;
  }
  dcnt[t] = incl - v;
}

__global__ __launch_bounds__(256) void k_nperm(const int* __restrict__ dcnt,
    const int* __restrict__ brank, const int* __restrict__ bidx,
    int* __restrict__ nperm) {
  int n = blockIdx.x * 256 + threadIdx.x;
  nperm[dcnt[bidx[n]] + brank[n]] = n;
}

// statically-named batch macros (NO dynamic indexing — round-12 lesson)
#define LOADREC8(rX, rbase)                                   \
  _Pragma("unroll") for (int k = 0; k < 8; k++) rX[k] = erec[(rbase) + k];
#define GATHER8(rX, hX, tX)                                   \
  _Pragma("unroll") for (int k = 0; k < 8; k++) {             \
    size_t s16 = (size_t)rX[k].x * 16;                        \
    hX[k] = hrow[s16];                                        \
    tX[k] = trow[s16];                                        \
  }
#define FMA8(rX, hX, tX)                                      \
  _Pragma("unroll") for (int k = 0; k < 8; k++) {             \
    float A0 = bflo(hX[k].x), A1 = bfhi(hX[k].x);             \
    float A2 = bflo(hX[k].y), A3 = bfhi(hX[k].y);             \
    float A4 = bflo(tX[k]);                                   \
    float f0 = bflo(rX[k].y), f1 = bfhi(rX[k].y);             \
    float f2 = bflo(rX[k].z), f3 = bfhi(rX[k].z);             \
    R[0][0] += f0 * A0; R[0][1] += f0 * A1; R[0][2] += f0 * A2; \
    R[0][3] += f0 * A3; R[0][4] += f0 * A4;                   \
    R[1][0] += f1 * A0; R[1][1] += f1 * A1; R[1][2] += f1 * A2; \
    R[1][3] += f1 * A3; R[1][4] += f1 * A4;                   \
    R[2][0] += f2 * A0; R[2][1] += f2 * A1; R[2][2] += f2 * A2; \
    R[2][3] += f2 * A3; R[2][4] += f2 * A4;                   \
    R[3][0] += f3 * A0; R[3][1] += f3 * A1; R[3][2] += f3 * A2; \
    R[3][3] += f3 * A3; R[3][4] += f3 * A4;                   \
  }

// ---------------- per-layer message + aggregate + post-matmul ----------------
// 8 nodes/block, quarter-wave per node, 3-batch-wide ILP block: 24 record
// loads + 48 gathers in flight before the first FMA consumes. (128,3) =
// 170-VGPR cap — (128,4) makes the allocator shrink to 64 and spill (r15).
__global__ __launch_bounds__(128, 3) void k_msg(const u16* __restrict__ hmain,
    const u16* __restrict__ htail, u16* __restrict__ omain,
    u16* __restrict__ otail,
    const float* __restrict__ w1, const float* __restrict__ w2,
    const float* __restrict__ w3, const float* __restrict__ w4,
    const int* __restrict__ offsets, const int* __restrict__ counts,
    const int* __restrict__ nperm, const uint4* __restrict__ erec) {
  __shared__ float Rlds[8][4][81];
  int tid = threadIdx.x;
  const int q = tid >> 4;
  const int c = tid & 15;
  const int n = nperm[blockIdx.x * 8 + q];

  float R[4][5];
#pragma unroll
  for (int j = 0; j < 4; j++)
#pragma unroll
    for (int i = 0; i < 5; i++) R[j][i] = 0.f;

  const int start = offsets[n];
  const int degp = (counts[n] + 7) & ~7;
  const int B = degp >> 3;
  const uint2* hrow = (const uint2*)hmain + c;
  const u16* trow = htail + c;

  int i = 0;
  for (; i + 3 <= B; i += 3) {
    const int base0 = start + 8 * i;
    uint4 rA[8], rB[8], rC[8];
    LOADREC8(rA, base0)
    LOADREC8(rB, base0 + 8)
    LOADREC8(rC, base0 + 16)
    uint2 hA[8], hB[8], hC[8];
    u32 tA[8], tB[8], tC[8];
    GATHER8(rA, hA, tA)
    GATHER8(rB, hB, tB)
    GATHER8(rC, hC, tC)
    FMA8(rA, hA, tA)
    FMA8(rB, hB, tB)
    FMA8(rC, hC, tC)
  }
  if (i + 2 <= B) {
    const int base0 = start + 8 * i;
    uint4 rA[8], rB[8];
    LOADREC8(rA, base0)
    LOADREC8(rB, base0 + 8)
    uint2 hA[8], hB[8];
    u32 tA[8], tB[8];
    GATHER8(rA, hA, tA)
    GATHER8(rB, hB, tB)
    FMA8(rA, hA, tA)
    FMA8(rB, hB, tB)
    i += 2;
  }
  if (i < B) {
    const int base0 = start + 8 * i;
    uint4 rA[8];
    LOADREC8(rA, base0)
    uint2 hA[8];
    u32 tA[8];
    GATHER8(rA, hA, tA)
    FMA8(rA, hA, tA)
  }

  // transpose into component-indexed LDS (quarter-private slice, wave-sync)
#pragma unroll
  for (int j = 0; j < 4; j++) {
#pragma unroll
    for (int k = 0; k < 4; k++) Rlds[q][j][4 * c + k] = R[j][k];
    Rlds[q][j][64 + c] = R[j][4];
  }

  // norm constants: 1/sqrt2 * path fan-in norm * 1/sqrt(DEG)
  const float C1 = 0.03125f;      // 1/(sqrt2*sqrt32*4)
  const float C2 = 0.025515518f;  // 1/(sqrt2*sqrt48*4)
  const float C3 = 0.03125f;      // 1/(sqrt2*sqrt32*4)
  const float C4 = 0.044194174f;  // 1/(sqrt2*sqrt16*4)

  u16* opm = omain + (size_t)n * 64;

  // scalar outputs c and c+16, fused over a
  float s0 = 0.f, s1 = 0.f;
#pragma unroll
  for (int a = 0; a < 32; a++) {
    float rs = Rlds[q][0][a];
    s0 += rs * w1[a * 32 + c];
    s1 += rs * w1[a * 32 + c + 16];
  }
  float t0 = 0.f, t1 = 0.f;
#pragma unroll
  for (int a = 0; a < 16; a++) {
    float T = Rlds[q][1][32 + 3 * a] + Rlds[q][2][33 + 3 * a] +
              Rlds[q][3][34 + 3 * a];
    t0 += T * w2[a * 32 + c];
    t1 += T * w2[a * 32 + c + 16];
  }
  opm[c] = f2bf(C1 * s0 + C2 * t0);
  opm[c + 16] = f2bf(C1 * s1 + C2 * t1);

  // vector outputs: logical comps c2 = 32 + 16*i + c.
#pragma unroll
  for (int v2 = 0; v2 < 3; v2++) {
    int c2 = 32 + 16 * v2 + c;
    int cv = (c2 - 32) / 3, k = (c2 - 32) % 3;
    float a3 = 0.f, a4 = 0.f;
#pragma unroll
    for (int a = 0; a < 32; a++) a3 += Rlds[q][k + 1][a] * w3[a * 16 + cv];
#pragma unroll
    for (int a = 0; a < 16; a++)
      a4 += Rlds[q][0][32 + 3 * a + k] * w4[a * 16 + cv];
    u16 v = f2bf(C3 * a3 + C4 * a4);
    if (v2 < 2) opm[32 + 16 * v2 + c] = v;
    else otail[(size_t)n * 16 + c] = v;
  }
}

// ---------------- output projection: out = relu(h) @ W_out + b_out ----------------
__global__ __launch_bounds__(256) void k_out(const u16* __restrict__ hmain,
    const u16* __restrict__ htail, const float* __restrict__ W,
    const float* __restrict__ b, float* __restrict__ out) {
  int idx = blockIdx.x * 256 + threadIdx.x;
  if (idx >= NN * 8) return;
  int n = idx >> 3, c = idx & 7;
  const uint2* hr = (const uint2*)(hmain + (size_t)n * 64);
  const u32* tr = (const u32*)(htail + (size_t)n * 16);
  float acc = b[c];
#pragma unroll
  for (int cc = 0; cc < 16; cc++) {
    uint2 v = hr[cc];
    float v0 = bflo(v.x), v1 = bfhi(v.x), v2 = bflo(v.y), v3 = bfhi(v.y);
    v0 = v0 > 0.f ? v0 : 0.f;
    v1 = v1 > 0.f ? v1 : 0.f;
    v2 = v2 > 0.f ? v2 : 0.f;
    v3 = v3 > 0.f ? v3 : 0.f;
    acc += v0 * W[(4 * cc) * 8 + c] + v1 * W[(4 * cc + 1) * 8 + c] +
           v2 * W[(4 * cc + 2) * 8 + c] + v3 * W[(4 * cc + 3) * 8 + c];
  }
#pragma unroll
  for (int k = 0; k < 8; k++) {
    u32 v = tr[k];
    float v0 = bflo(v), v1 = bfhi(v);
    v0 = v0 > 0.f ? v0 : 0.f;
    v1 = v1 > 0.f ? v1 : 0.f;
    acc += v0 * W[(64 + 2 * k) * 8 + c] + v1 * W[(64 + 2 * k + 1) * 8 + c];
  }
  out[idx] = acc;
}

extern "C" void kernel_launch(void* const* d_in, const int* in_sizes, int n_in,
                              void* d_out, int out_size, void* d_ws,
                              size_t ws_size, hipStream_t stream) {
  const float* x = (const float*)d_in[0];
  const int* ei = (const int*)d_in[1];
  const float* eattr = (const float*)d_in[2];
  const float* W_in = (const float*)d_in[3];
  const float* b_in = (const float*)d_in[4];
  const float* tp_w1 = (const float*)d_in[5];
  const float* tp_w2 = (const float*)d_in[6];
  const float* tp_w3 = (const float*)d_in[7];
  const float* tp_w4 = (const float*)d_in[8];
  const float* W_out = (const float*)d_in[9];
  const float* b_out = (const float*)d_in[10];
  float* out = (float*)d_out;

  char* ws = (char*)d_ws;
  size_t off = 0;
  auto alloc = [&](size_t bytes) {
    void* p = ws + off;
    off += (bytes + 255) & ~size_t(255);
    return p;
  };
  const size_t NEP = (size_t)NE + 8 * (size_t)NN;
  u16* hm_a = (u16*)alloc((size_t)NN * 64 * 2);
  u16* ht_a = (u16*)alloc((size_t)NN * 16 * 2);
  u16* hm_b = (u16*)alloc((size_t)NN * 64 * 2);
  u16* ht_b = (u16*)alloc((size_t)NN * 16 * 2);
  int* counts = (int*)alloc((size_t)NN * 4);
  int* offsets = (int*)alloc((size_t)NN * 4);
  int* blocksum = (int*)alloc(64 * 4);
  int* rank = (int*)alloc((size_t)NE * 4);
  int* dcnt = (int*)alloc(16 * 4);
  int* brank = (int*)alloc((size_t)NN * 4);
  int* bidx = (int*)alloc((size_t)NN * 4);
  int* nperm = (int*)alloc((size_t)NN * 4);
  uint4* erec = (uint4*)alloc(NEP * 16);

  const int* src = ei;
  const int* dst = ei + NE;

  hipMemsetAsync(counts, 0, (size_t)NN * 4, stream);
  hipMemsetAsync(dcnt, 0, 16 * 4, stream);
  k_in<<<(NN * HID + 255) / 256, 256, 0, stream>>>(x, W_in, b_in, hm_a, ht_a);
  k_hist<<<NE / 1024, 256, 0, stream>>>(dst, counts, rank);
  k_scan1<<<64, 256, 0, stream>>>(counts, offsets, blocksum);
  k_scan2<<<1, 64, 0, stream>>>(blocksum);
  k_scan3<<<256, 256, 0, stream>>>(offsets, blocksum);
  k_pad<<<NN / 256, 256, 0, stream>>>(counts, offsets, erec);
  k_nbucket<<<NN / 256, 256, 0, stream>>>(counts, dcnt, brank, bidx);
  k_dscan<<<1, 64, 0, stream>>>(dcnt);
  k_nperm<<<NN / 256, 256, 0, stream>>>(dcnt, brank, bidx, nperm);
  k_fill<<<NE / 1024, 256, 0, stream>>>(src, dst, (const float4*)eattr,
                                        offsets, rank, erec);

  u16* hmi = hm_a;
  u16* hti = ht_a;
  u16* hmo = hm_b;
  u16* hto = ht_b;
  for (int l = 0; l < 3; l++) {
    k_msg<<<NN / 8, 128, 0, stream>>>(hmi, hti, hmo, hto, tp_w1 + l * 1024,
                                      tp_w2 + l * 512, tp_w3 + l * 512,
                                      tp_w4 + l * 256, offsets, counts, nperm,
                                      erec);
    u16* t;
    t = hmi; hmi = hmo; hmo = t;
    t = hti; hti = hto; hto = t;
  }
  k_out<<<(NN * 8 + 255) / 256, 256, 0, stream>>>(hmi, hti, W_out, b_out, out);
}

// Round 17
// 397.449 us; speedup vs baseline: 1.1170x; 1.1170x over previous
//
#include <hip/hip_runtime.h>

#define NN 65536
#define NE 1048576
#define HID 80

typedef unsigned int u32;
typedef unsigned short u16;
typedef unsigned long long u64;

__device__ __forceinline__ u16 f2bf(float f) {
  u32 u = __float_as_uint(f);
  u = (u + 0x7fffu + ((u >> 16) & 1u)) >> 16;  // RNE
  return (u16)u;
}
__device__ __forceinline__ float bfhi(u32 packed) {
  return __uint_as_float(packed & 0xffff0000u);
}
__device__ __forceinline__ float bflo(u32 packed) {
  return __uint_as_float(packed << 16);
}

// ---------------- input projection: h = x @ W_in + b_in ----------------
// hmain[n][64] = logical comps 0..63; htail[n][16] = comps 64..79 (L2-res.)
__global__ __launch_bounds__(256) void k_in(const float* __restrict__ x,
    const float* __restrict__ W, const float* __restrict__ b,
    u16* __restrict__ hmain, u16* __restrict__ htail) {
  int idx = blockIdx.x * 256 + threadIdx.x;
  if (idx >= NN * HID) return;
  int n = idx / HID, l = idx % HID;
  const float* xr = x + n * 16;
  float acc = b[l];
#pragma unroll
  for (int k = 0; k < 16; k++) acc += xr[k] * W[k * HID + l];
  u16 v = f2bf(acc);
  if (l < 64) hmain[(size_t)n * 64 + l] = v;
  else htail[(size_t)n * 16 + (l - 64)] = v;
}

// ---------------- CSR build ----------------
// hist + per-edge rank, batched x8 (8 independent atomic chains/thread)
__global__ __launch_bounds__(256) void k_hist(const int* __restrict__ dst,
    int* __restrict__ counts, int* __restrict__ rank) {
  int base = blockIdx.x * 2048 + threadIdx.x;
#pragma unroll
  for (int k = 0; k < 8; k++) {
    int idx = base + k * 256;
    rank[idx] = atomicAdd(&counts[dst[idx]], 1);
  }
}

// exclusive scan of counts PADDED to multiples of 8
__global__ __launch_bounds__(256) void k_scan1(const int* __restrict__ counts,
    int* __restrict__ offsets, int* __restrict__ blocksum) {
  __shared__ int sc[256];
  int t = threadIdx.x;
  int base = blockIdx.x * 1024 + t * 4;
  int p0 = (counts[base] + 7) & ~7;
  int p1 = (counts[base + 1] + 7) & ~7;
  int p2 = (counts[base + 2] + 7) & ~7;
  int p3 = (counts[base + 3] + 7) & ~7;
  int s = p0 + p1 + p2 + p3;
  sc[t] = s;
  __syncthreads();
  for (int d = 1; d < 256; d <<= 1) {
    int v = (t >= d) ? sc[t - d] : 0;
    __syncthreads();
    sc[t] += v;
    __syncthreads();
  }
  int excl = sc[t] - s;
  offsets[base] = excl;
  offsets[base + 1] = excl + p0;
  offsets[base + 2] = excl + p0 + p1;
  offsets[base + 3] = excl + p0 + p1 + p2;
  if (t == 255) blocksum[blockIdx.x] = sc[255];
}

// block 0: scan blocksum[64]; block 1: scan dcnt[16]  (merged, saves a launch)
__global__ __launch_bounds__(64) void k_scan2(int* __restrict__ blocksum,
                                              int* __restrict__ dcnt) {
  int t = threadIdx.x;
  if (blockIdx.x == 0) {
    int v = blocksum[t];
    int incl = v;
#pragma unroll
    for (int d = 1; d < 64; d <<= 1) {
      int o = __shfl_up(incl, d, 64);
      if (t >= d) incl += o;
    }
    blocksum[t] = incl - v;
  } else {
    if (t >= 16) return;
    int v = dcnt[t];
    int incl = v;
#pragma unroll
    for (int d = 1; d < 16; d <<= 1) {
      int o = __shfl_up(incl, d, 64);
      if (t >= d) incl += o;
    }
    dcnt[t] = incl - v;
  }
}

// ---------------- degree-bucket node sort ----------------
// reversed buckets: heaviest-degree nodes dispatch first (straggler fix)
__global__ __launch_bounds__(256) void k_nbucket(const int* __restrict__ counts,
    int* __restrict__ dcnt, int* __restrict__ brank, int* __restrict__ bidx) {
  int n = blockIdx.x * 256 + threadIdx.x;
  int degp = (counts[n] + 7) & ~7;
  int b = 15 - min(degp >> 3, 15);
  int lane = threadIdx.x & 63;
  int base = 0;
#pragma unroll 1
  for (int bb = 0; bb < 16; bb++) {
    u64 m = __ballot(b == bb);
    if (b == bb) {
      int leader = __ffsll((long long)m) - 1;
      int lr = __popcll(m & ((lane == 63) ? ~0ull >> 1 : ((1ull << lane) - 1)));
      int bs = 0;
      if (lane == leader) bs = atomicAdd(&dcnt[bb], __popcll(m));
      bs = __shfl(bs, leader, 64);
      base = bs + lr;
    }
  }
  brank[n] = base;
  bidx[n] = b;
}

// merged per-node finalize: offsets += blocksum (scan3) + zero pad slots
// (k_pad) + write nperm (k_nperm). Saves 2 launches + re-reads.
__global__ __launch_bounds__(256) void k_node_fin(int* __restrict__ offsets,
    const int* __restrict__ blocksum, const int* __restrict__ counts,
    uint4* __restrict__ erec, const int* __restrict__ dcnt,
    const int* __restrict__ brank, const int* __restrict__ bidx,
    int* __restrict__ nperm) {
  int n = blockIdx.x * 256 + threadIdx.x;
  int off = offsets[n] + blocksum[n >> 10];
  offsets[n] = off;
  int deg = counts[n];
  int degp = (deg + 7) & ~7;
  uint4 z = make_uint4(0u, 0u, 0u, 0u);
  for (int e = deg; e < degp; e++) erec[off + e] = z;
  nperm[dcnt[bidx[n]] + brank[n]] = n;
}

// pure scatter, no atomic: pos = offsets[dst] + rank   (batched x8)
__global__ __launch_bounds__(256) void k_fill(const int* __restrict__ src,
    const int* __restrict__ dst, const float4* __restrict__ eattr,
    const int* __restrict__ offsets, const int* __restrict__ rank,
    uint4* __restrict__ erec) {
  int base = blockIdx.x * 2048 + threadIdx.x;
#pragma unroll
  for (int k = 0; k < 8; k++) {
    int idx = base + k * 256;
    int d = dst[idx];
    float4 ea = eattr[idx];
    int s = src[idx];
    u32 c01 = (u32)f2bf(ea.x) | ((u32)f2bf(ea.y) << 16);
    u32 c23 = (u32)f2bf(ea.z) | ((u32)f2bf(ea.w) << 16);
    int pos = offsets[d] + rank[idx];
    erec[pos] = make_uint4((u32)s, c01, c23, 0u);
  }
}

// ---------------- per-layer message + aggregate + post-matmul ----------------
// Round-14 proven optimum: 8 nodes/block, quarter-wave per node, manual
// 2-batch statically-indexed pipeline, (128,3) = 170-VGPR cap -> 76 VGPR,
// no spill. (128,4) shrinks alloc to 64 and spills (r15); 3-wide spills
// (r16). ~61 us = random-64B-line gather service bound (FETCH 86 MB at
// 1.4 TB/s); not VALU-, occupancy-, or bytes-bound.
__global__ __launch_bounds__(128, 3) void k_msg(const u16* __restrict__ hmain,
    const u16* __restrict__ htail, u16* __restrict__ omain,
    u16* __restrict__ otail,
    const float* __restrict__ w1, const float* __restrict__ w2,
    const float* __restrict__ w3, const float* __restrict__ w4,
    const int* __restrict__ offsets, const int* __restrict__ counts,
    const int* __restrict__ nperm, const uint4* __restrict__ erec) {
  __shared__ float Rlds[8][4][81];
  int tid = threadIdx.x;
  const int q = tid >> 4;
  const int c = tid & 15;
  const int n = nperm[blockIdx.x * 8 + q];

  float R[4][5];
#pragma unroll
  for (int j = 0; j < 4; j++)
#pragma unroll
    for (int i = 0; i < 5; i++) R[j][i] = 0.f;

  const int start = offsets[n];
  const int degp = (counts[n] + 7) & ~7;
  const int B = degp >> 3;
  const uint2* hrow = (const uint2*)hmain + c;
  const u16* trow = htail + c;

  int i = 0;
  for (; i + 2 <= B; i += 2) {
    const int baseA = start + 8 * i;
    const int baseB = baseA + 8;
    uint4 rA[8], rB[8];
#pragma unroll
    for (int k = 0; k < 8; k++) rA[k] = erec[baseA + k];
#pragma unroll
    for (int k = 0; k < 8; k++) rB[k] = erec[baseB + k];
    uint2 hA[8], hB[8];
    u32 tA[8], tB[8];
#pragma unroll
    for (int k = 0; k < 8; k++) {
      size_t s16 = (size_t)rA[k].x * 16;
      hA[k] = hrow[s16];
      tA[k] = trow[s16];
    }
#pragma unroll
    for (int k = 0; k < 8; k++) {
      size_t s16 = (size_t)rB[k].x * 16;
      hB[k] = hrow[s16];
      tB[k] = trow[s16];
    }
#pragma unroll
    for (int k = 0; k < 8; k++) {
      float A0 = bflo(hA[k].x), A1 = bfhi(hA[k].x);
      float A2 = bflo(hA[k].y), A3 = bfhi(hA[k].y);
      float A4 = bflo(tA[k]);
      float f0 = bflo(rA[k].y), f1 = bfhi(rA[k].y);
      float f2 = bflo(rA[k].z), f3 = bfhi(rA[k].z);
      R[0][0] += f0 * A0; R[0][1] += f0 * A1; R[0][2] += f0 * A2;
      R[0][3] += f0 * A3; R[0][4] += f0 * A4;
      R[1][0] += f1 * A0; R[1][1] += f1 * A1; R[1][2] += f1 * A2;
      R[1][3] += f1 * A3; R[1][4] += f1 * A4;
      R[2][0] += f2 * A0; R[2][1] += f2 * A1; R[2][2] += f2 * A2;
      R[2][3] += f2 * A3; R[2][4] += f2 * A4;
      R[3][0] += f3 * A0; R[3][1] += f3 * A1; R[3][2] += f3 * A2;
      R[3][3] += f3 * A3; R[3][4] += f3 * A4;
    }
#pragma unroll
    for (int k = 0; k < 8; k++) {
      float A0 = bflo(hB[k].x), A1 = bfhi(hB[k].x);
      float A2 = bflo(hB[k].y), A3 = bfhi(hB[k].y);
      float A4 = bflo(tB[k]);
      float f0 = bflo(rB[k].y), f1 = bfhi(rB[k].y);
      float f2 = bflo(rB[k].z), f3 = bfhi(rB[k].z);
      R[0][0] += f0 * A0; R[0][1] += f0 * A1; R[0][2] += f0 * A2;
      R[0][3] += f0 * A3; R[0][4] += f0 * A4;
      R[1][0] += f1 * A0; R[1][1] += f1 * A1; R[1][2] += f1 * A2;
      R[1][3] += f1 * A3; R[1][4] += f1 * A4;
      R[2][0] += f2 * A0; R[2][1] += f2 * A1; R[2][2] += f2 * A2;
      R[2][3] += f2 * A3; R[2][4] += f2 * A4;
      R[3][0] += f3 * A0; R[3][1] += f3 * A1; R[3][2] += f3 * A2;
      R[3][3] += f3 * A3; R[3][4] += f3 * A4;
    }
  }
  if (i < B) {
    const int baseA = start + 8 * i;
    uint4 rA[8];
#pragma unroll
    for (int k = 0; k < 8; k++) rA[k] = erec[baseA + k];
    uint2 hA[8];
    u32 tA[8];
#pragma unroll
    for (int k = 0; k < 8; k++) {
      size_t s16 = (size_t)rA[k].x * 16;
      hA[k] = hrow[s16];
      tA[k] = trow[s16];
    }
#pragma unroll
    for (int k = 0; k < 8; k++) {
      float A0 = bflo(hA[k].x), A1 = bfhi(hA[k].x);
      float A2 = bflo(hA[k].y), A3 = bfhi(hA[k].y);
      float A4 = bflo(tA[k]);
      float f0 = bflo(rA[k].y), f1 = bfhi(rA[k].y);
      float f2 = bflo(rA[k].z), f3 = bfhi(rA[k].z);
      R[0][0] += f0 * A0; R[0][1] += f0 * A1; R[0][2] += f0 * A2;
      R[0][3] += f0 * A3; R[0][4] += f0 * A4;
      R[1][0] += f1 * A0; R[1][1] += f1 * A1; R[1][2] += f1 * A2;
      R[1][3] += f1 * A3; R[1][4] += f1 * A4;
      R[2][0] += f2 * A0; R[2][1] += f2 * A1; R[2][2] += f2 * A2;
      R[2][3] += f2 * A3; R[2][4] += f2 * A4;
      R[3][0] += f3 * A0; R[3][1] += f3 * A1; R[3][2] += f3 * A2;
      R[3][3] += f3 * A3; R[3][4] += f3 * A4;
    }
  }

  // transpose into component-indexed LDS (quarter-private slice, wave-sync)
#pragma unroll
  for (int j = 0; j < 4; j++) {
#pragma unroll
    for (int k = 0; k < 4; k++) Rlds[q][j][4 * c + k] = R[j][k];
    Rlds[q][j][64 + c] = R[j][4];
  }

  // norm constants: 1/sqrt2 * path fan-in norm * 1/sqrt(DEG)
  const float C1 = 0.03125f;      // 1/(sqrt2*sqrt32*4)
  const float C2 = 0.025515518f;  // 1/(sqrt2*sqrt48*4)
  const float C3 = 0.03125f;      // 1/(sqrt2*sqrt32*4)
  const float C4 = 0.044194174f;  // 1/(sqrt2*sqrt16*4)

  u16* opm = omain + (size_t)n * 64;

  // scalar outputs c and c+16, fused over a
  float s0 = 0.f, s1 = 0.f;
#pragma unroll
  for (int a = 0; a < 32; a++) {
    float rs = Rlds[q][0][a];
    s0 += rs * w1[a * 32 + c];
    s1 += rs * w1[a * 32 + c + 16];
  }
  float t0 = 0.f, t1 = 0.f;
#pragma unroll
  for (int a = 0; a < 16; a++) {
    float T = Rlds[q][1][32 + 3 * a] + Rlds[q][2][33 + 3 * a] +
              Rlds[q][3][34 + 3 * a];
    t0 += T * w2[a * 32 + c];
    t1 += T * w2[a * 32 + c + 16];
  }
  opm[c] = f2bf(C1 * s0 + C2 * t0);
  opm[c + 16] = f2bf(C1 * s1 + C2 * t1);

  // vector outputs: logical comps c2 = 32 + 16*i + c.
#pragma unroll
  for (int v2 = 0; v2 < 3; v2++) {
    int c2 = 32 + 16 * v2 + c;
    int cv = (c2 - 32) / 3, k = (c2 - 32) % 3;
    float a3 = 0.f, a4 = 0.f;
#pragma unroll
    for (int a = 0; a < 32; a++) a3 += Rlds[q][k + 1][a] * w3[a * 16 + cv];
#pragma unroll
    for (int a = 0; a < 16; a++)
      a4 += Rlds[q][0][32 + 3 * a + k] * w4[a * 16 + cv];
    u16 v = f2bf(C3 * a3 + C4 * a4);
    if (v2 < 2) opm[32 + 16 * v2 + c] = v;
    else otail[(size_t)n * 16 + c] = v;
  }
}

// ---------------- output projection: out = relu(h) @ W_out + b_out ----------------
__global__ __launch_bounds__(256) void k_out(const u16* __restrict__ hmain,
    const u16* __restrict__ htail, const float* __restrict__ W,
    const float* __restrict__ b, float* __restrict__ out) {
  int idx = blockIdx.x * 256 + threadIdx.x;
  if (idx >= NN * 8) return;
  int n = idx >> 3, c = idx & 7;
  const uint2* hr = (const uint2*)(hmain + (size_t)n * 64);
  const u32* tr = (const u32*)(htail + (size_t)n * 16);
  float acc = b[c];
#pragma unroll
  for (int cc = 0; cc < 16; cc++) {
    uint2 v = hr[cc];
    float v0 = bflo(v.x), v1 = bfhi(v.x), v2 = bflo(v.y), v3 = bfhi(v.y);
    v0 = v0 > 0.f ? v0 : 0.f;
    v1 = v1 > 0.f ? v1 : 0.f;
    v2 = v2 > 0.f ? v2 : 0.f;
    v3 = v3 > 0.f ? v3 : 0.f;
    acc += v0 * W[(4 * cc) * 8 + c] + v1 * W[(4 * cc + 1) * 8 + c] +
           v2 * W[(4 * cc + 2) * 8 + c] + v3 * W[(4 * cc + 3) * 8 + c];
  }
#pragma unroll
  for (int k = 0; k < 8; k++) {
    u32 v = tr[k];
    float v0 = bflo(v), v1 = bfhi(v);
    v0 = v0 > 0.f ? v0 : 0.f;
    v1 = v1 > 0.f ? v1 : 0.f;
    acc += v0 * W[(64 + 2 * k) * 8 + c] + v1 * W[(64 + 2 * k + 1) * 8 + c];
  }
  out[idx] = acc;
}

extern "C" void kernel_launch(void* const* d_in, const int* in_sizes, int n_in,
                              void* d_out, int out_size, void* d_ws,
                              size_t ws_size, hipStream_t stream) {
  const float* x = (const float*)d_in[0];
  const int* ei = (const int*)d_in[1];
  const float* eattr = (const float*)d_in[2];
  const float* W_in = (const float*)d_in[3];
  const float* b_in = (const float*)d_in[4];
  const float* tp_w1 = (const float*)d_in[5];
  const float* tp_w2 = (const float*)d_in[6];
  const float* tp_w3 = (const float*)d_in[7];
  const float* tp_w4 = (const float*)d_in[8];
  const float* W_out = (const float*)d_in[9];
  const float* b_out = (const float*)d_in[10];
  float* out = (float*)d_out;

  char* ws = (char*)d_ws;
  size_t off = 0;
  auto alloc = [&](size_t bytes) {
    void* p = ws + off;
    off += (bytes + 255) & ~size_t(255);
    return p;
  };
  const size_t NEP = (size_t)NE + 8 * (size_t)NN;
  u16* hm_a = (u16*)alloc((size_t)NN * 64 * 2);
  u16* ht_a = (u16*)alloc((size_t)NN * 16 * 2);
  u16* hm_b = (u16*)alloc((size_t)NN * 64 * 2);
  u16* ht_b = (u16*)alloc((size_t)NN * 16 * 2);
  int* counts = (int*)alloc((size_t)NN * 4);
  int* offsets = (int*)alloc((size_t)NN * 4);
  int* blocksum = (int*)alloc(64 * 4);
  int* rank = (int*)alloc((size_t)NE * 4);
  int* dcnt = (int*)alloc(16 * 4);
  int* brank = (int*)alloc((size_t)NN * 4);
  int* bidx = (int*)alloc((size_t)NN * 4);
  int* nperm = (int*)alloc((size_t)NN * 4);
  uint4* erec = (uint4*)alloc(NEP * 16);

  const int* src = ei;
  const int* dst = ei + NE;

  hipMemsetAsync(counts, 0, (size_t)NN * 4, stream);
  hipMemsetAsync(dcnt, 0, 16 * 4, stream);
  k_in<<<(NN * HID + 255) / 256, 256, 0, stream>>>(x, W_in, b_in, hm_a, ht_a);
  k_hist<<<NE / 2048, 256, 0, stream>>>(dst, counts, rank);
  k_nbucket<<<NN / 256, 256, 0, stream>>>(counts, dcnt, brank, bidx);
  k_scan1<<<64, 256, 0, stream>>>(counts, offsets, blocksum);
  k_scan2<<<2, 64, 0, stream>>>(blocksum, dcnt);
  k_node_fin<<<NN / 256, 256, 0, stream>>>(offsets, blocksum, counts, erec,
                                           dcnt, brank, bidx, nperm);
  k_fill<<<NE / 2048, 256, 0, stream>>>(src, dst, (const float4*)eattr,
                                        offsets, rank, erec);

  u16* hmi = hm_a;
  u16* hti = ht_a;
  u16* hmo = hm_b;
  u16* hto = ht_b;
  for (int l = 0; l < 3; l++) {
    k_msg<<<NN / 8, 128, 0, stream>>>(hmi, hti, hmo, hto, tp_w1 + l * 1024,
                                      tp_w2 + l * 512, tp_w3 + l * 512,
                                      tp_w4 + l * 256, offsets, counts, nperm,
                                      erec);
    u16* t;
    t = hmi; hmi = hmo; hmo = t;
    t = hti; hti = hto; hto = t;
  }
  k_out<<<(NN * 8 + 255) / 256, 256, 0, stream>>>(hmi, hti, W_out, b_out, out);
}